// Round 12
// baseline (547.256 us; speedup 1.0000x reference)
//
#include <hip/hip_runtime.h>
#include <hip/hip_bf16.h>
#include <stdint.h>

// SpatioConvLayer: out = relu(x + b + einsum('iok,knm,bitm->botn', theta, Lk, x))
// (1) BT[n][k*1024+m] = bf16(Lk[k][n][m]); (2) Y[(b*48+t)*64+o][k*1024+m]
//     = sum_i theta[i,o,k] * x[b,i,t,m] (bf16, MFMA, LDS-staged x); (3) out =
//     Y @ BT^T fused bias+residual+relu, 256x256x64, MFMA 32x32x16.
// R12: single barrier per K-tile, no intra-tile fences (compiler free-
//      schedules 24 ds_read + 8 stage-gloads + 32 MFMA). LDS budget fixed:
//      A 3-deep (96KB, staged t+2) + B 2-deep (64KB, staged t+1) = 160KB
//      exactly. VMC(4) counted per tile (A(t+2) stays in flight).

typedef short bs8 __attribute__((ext_vector_type(8)));     // 8 x bf16 fragment
typedef float f32x4 __attribute__((ext_vector_type(4)));   // 16x16 accumulator
typedef float f32x16 __attribute__((ext_vector_type(16))); // 32x32 accumulator

#define NB   16
#define NC   64
#define NT   48
#define NN   1024
#define NKS  3
#define KDIM 3072  // NKS * NN
#define KT   48    // KDIM / 64 K-tiles

// f32 -> bf16 round-to-nearest-even (finite inputs only)
__device__ __forceinline__ short f2bs(float f) {
  uint32_t u = __builtin_bit_cast(uint32_t, f);
  u = (u + 0x7FFFu + ((u >> 16) & 1u)) >> 16;
  return (short)u;
}

__device__ __forceinline__ void gload16(const void* g, void* l) {
  __builtin_amdgcn_global_load_lds(
      (const __attribute__((address_space(1))) void*)g,
      (__attribute__((address_space(3))) void*)l, 16, 0, 0);
}

// ---------------- prep: BT[n][k*NN+m] = bf16(Lk[k][n][m]) -------------------
__global__ __launch_bounds__(256) void k_prep_bt(const float* __restrict__ Lk,
                                                 short* __restrict__ BT) {
  int gid = blockIdx.x * 256 + threadIdx.x;
  int e = gid * 4;
  int k = e >> 20;
  int rem = e & 1048575;
  int n = rem >> 10;
  int m = rem & 1023;
  float4 v = *reinterpret_cast<const float4*>(Lk + e);
  union { short s[4]; uint64_t u; } p;
  p.s[0] = f2bs(v.x); p.s[1] = f2bs(v.y); p.s[2] = f2bs(v.z); p.s[3] = f2bs(v.w);
  *reinterpret_cast<uint64_t*>(BT + (size_t)n * KDIM + k * NN + m) = p.u;
}

// ---------------- step1: Y[btl*64+o][k*NN+m] = sum_i th[i,o,k] x[b,i,t,m] ---
__global__ __launch_bounds__(256, 2) void k_step1(const float* __restrict__ x,
                                                  const float* __restrict__ theta,
                                                  short* __restrict__ Y, int b0) {
  __shared__ __align__(16) short th[NKS * 64 * 72];  // [k][o][i] padded, 27.6KB
  __shared__ __align__(16) float xs[64 * 128];       // [i][m] slice, 32KB
  int tid = threadIdx.x;
  int wave = tid >> 6;
  for (int idx = tid; idx < NC * NC * NKS; idx += 256) {
    int i = idx / (NC * NKS);
    int r = idx - i * (NC * NKS);
    int o = r / NKS;
    int k = r - o * NKS;
    th[(k * 64 + o) * 72 + i] = f2bs(theta[idx]);  // theta[i][o][k]
  }

  int bid = blockIdx.x;
  int mt  = bid & 7;            // m-tile of 128
  int btl = bid >> 3;
  int b_l = btl / NT;
  int t   = btl - b_l * NT;
  int b   = b0 + b_l;
  const float* xb = x + (size_t)b * (NC * NT * NN) + (size_t)t * NN + mt * 128;

#pragma unroll
  for (int c = 0; c < 8; ++c) {
    int idx = c * 256 + tid;
    int row = idx >> 5, ch = idx & 31;
    gload16(xb + (size_t)row * (NT * NN) + ch * 4,
            xs + (c * 256 + wave * 64) * 4);  // wave-uniform base, 16B/lane
  }
  __syncthreads();  // drains vmcnt (xs) + lgkm (th)

  int lane = tid & 63;
  int l15 = lane & 15, lg = lane >> 4;
  size_t yrow0 = (size_t)btl * 64;

  for (int nni = 0; nni < 2; ++nni) {
    int mloc = wave * 32 + nni * 16 + l15;
    float xv[16];
#pragma unroll
    for (int j = 0; j < 16; ++j) {
      int i = ((j >> 3) << 5) + lg * 8 + (j & 7);
      xv[j] = xs[i * 128 + mloc];
    }
    f32x4 acc[3][4];
#pragma unroll
    for (int k = 0; k < 3; ++k)
#pragma unroll
      for (int mi = 0; mi < 4; ++mi)
        acc[k][mi] = (f32x4){0.f, 0.f, 0.f, 0.f};

#pragma unroll
    for (int ks = 0; ks < 2; ++ks) {
      bs8 bfrag;
#pragma unroll
      for (int j = 0; j < 8; ++j) bfrag[j] = f2bs(xv[ks * 8 + j]);
#pragma unroll
      for (int mi = 0; mi < 4; ++mi) {
#pragma unroll
        for (int k = 0; k < 3; ++k) {
          const bs8* ap = reinterpret_cast<const bs8*>(
              &th[(k * 64 + mi * 16 + l15) * 72 + ks * 32 + lg * 8]);
          acc[k][mi] = __builtin_amdgcn_mfma_f32_16x16x32_bf16(
              *ap, bfrag, acc[k][mi], 0, 0, 0);
        }
      }
    }
    int mcol = mt * 128 + mloc;
#pragma unroll
    for (int k = 0; k < 3; ++k)
#pragma unroll
      for (int mi = 0; mi < 4; ++mi)
#pragma unroll
        for (int q = 0; q < 4; ++q) {
          int o = mi * 16 + lg * 4 + q;
          Y[(yrow0 + o) * KDIM + k * NN + mcol] = f2bs(acc[k][mi][q]);
        }
  }
}

// ---------------- big GEMM: C = Y @ BT^T, 256^2, 32x32x16, 1 bar/tile -------
// 8 waves 2M x 4N. Per tile: 16 A + 8 B ds_read_b128, 32 MFMA, stage
// B(t+1)->BL[(t+1)%2] then A(t+2)->AL[(t+2)%3] (order matters for vmcnt),
// all unfenced; then VMC(4) + s_barrier.
// vmcnt ledger: outstanding at tile-t VMC (old->new): A(t+1),B(t+1),A(t+2);
// need A(t+1)&B(t+1) -> VMC(4) leaves A(t+2) in flight (never drain-0).
// Slot races: stage_B(t+1) overwrites B(t-1), consumed before BARR(t-1),
// stage issues post-BARR(t-1); stage_A(t+2) overwrites A(t-1), same. Tails:
// t=46 stages B(47) only, VMC(0); t=47 bare. Prologue A(0),B(0),A(1),VMC(4).
// Swizzle: LDS[row][c8] = global[row][c8 ^ g(row)], g=(row&7)^((row>>3)&3).

__device__ __forceinline__ void stage_tile(const short* __restrict__ src,
                                           short* lds, int tid) {
#pragma unroll
  for (int c = 0; c < 4; ++c) {
    int idx = c * 512 + tid;                      // 0..2047: 256 rows x 8 c8
    int row = idx >> 3, c8 = idx & 7;
    int c8s = c8 ^ (row & 7) ^ ((row >> 3) & 3);  // inverse-swizzled source
    gload16(src + (size_t)row * KDIM + c8s * 8, lds + idx * 8);
  }
}

#define VMC(N) asm volatile("s_waitcnt vmcnt(" #N ")" ::: "memory")
#define BARR() __builtin_amdgcn_s_barrier();

#define READ_A32(DST, MP, P)                                                \
  _Pragma("unroll") for (int e = 0; e < 2; ++e)                             \
    _Pragma("unroll") for (int ks = 0; ks < 4; ++ks) {                      \
      int row = (4 * (MP) + 2 * e + wr) * 32 + l31;                         \
      int ch = (2 * ks + hi) ^ (row & 7) ^ ((row >> 3) & 3);                \
      DST[e][ks] = *(const bs8*)&AL[(P) * 16384 + row * 64 + ch * 8];       \
    }

#define READ_B32(DST, NI, P)                                                \
  _Pragma("unroll") for (int ks = 0; ks < 4; ++ks) {                        \
    int row = (4 * (NI) + wc) * 32 + l31;                                   \
    int ch = (2 * ks + hi) ^ (row & 7) ^ ((row >> 3) & 3);                  \
    DST[ks] = *(const bs8*)&BL[(P) * 16384 + row * 64 + ch * 8];            \
  }

#define COMPUTE32(MP, BF, NI)                                               \
  __builtin_amdgcn_s_setprio(1);                                            \
  _Pragma("unroll") for (int ks = 0; ks < 4; ++ks)                          \
    _Pragma("unroll") for (int e = 0; e < 2; ++e)                           \
      acc[2 * (MP) + e][(NI)] = __builtin_amdgcn_mfma_f32_32x32x16_bf16(    \
          af[e][ks], BF[ks], acc[2 * (MP) + e][(NI)], 0, 0, 0);             \
  __builtin_amdgcn_s_setprio(0);

// PA: A buf (t%3); PB: B buf (t%2); SB: stage B(t+1); SA: stage A(t+2).
#define TILE(t, PA, PB, SB, SA, VM, BR)                                     \
  {                                                                         \
    bs8 af[2][4], bf0[4], bf1[4];                                           \
    READ_A32(af, 0, PA);                                                    \
    READ_B32(bf0, 0, PB);                                                   \
    if (SB) stage_tile(BTb + ((t) + 1) * 64, BL + ((PB) ^ 1) * 16384, tid); \
    if (SA) stage_tile(Yb + ((t) + 2) * 64,                                 \
                       AL + (((PA) + 2) % 3) * 16384, tid);                 \
    COMPUTE32(0, bf0, 0);                                                   \
    READ_B32(bf1, 1, PB);                                                   \
    COMPUTE32(0, bf1, 1);                                                   \
    READ_A32(af, 1, PA);                                                    \
    COMPUTE32(1, bf1, 1);                                                   \
    COMPUTE32(1, bf0, 0);                                                   \
    VM;                                                                     \
    BR;                                                                     \
  }

__global__ __launch_bounds__(512, 2) void k_gemm(const short* __restrict__ Y,
                                                 const short* __restrict__ BT,
                                                 const float* __restrict__ x,
                                                 const float* __restrict__ bias,
                                                 float* __restrict__ out,
                                                 int b0, int nwg) {
  __shared__ __align__(16) short AL[3 * 16384];  // [3 bufs][256][64] 96 KiB
  __shared__ __align__(16) short BL[2 * 16384];  // [2 bufs][256][64] 64 KiB

  int bid = blockIdx.x;
  int cpx = nwg >> 3;                        // nwg % 8 == 0 -> bijective
  int swz = (bid & 7) * cpx + (bid >> 3);    // XCD-aware swizzle
  int colb = swz & 3;                        // 4 col-blocks (N=1024/256)
  int rowb = swz >> 2;

  int tid = threadIdx.x;
  int lane = tid & 63, wave = tid >> 6;
  int wr = wave >> 2, wc = wave & 3;         // 2M x 4N waves
  int l31 = lane & 31, hi = lane >> 5;
  int row0 = rowb * 256, col0 = colb * 256;

  const short* Yb  = Y  + (size_t)row0 * KDIM;
  const short* BTb = BT + (size_t)col0 * KDIM;

  f32x16 acc[4][2];                          // [a = 2MP+e][NI]; mf = 2a+wr
#pragma unroll
  for (int a = 0; a < 4; ++a)
#pragma unroll
    for (int i = 0; i < 2; ++i)
#pragma unroll
      for (int q = 0; q < 16; ++q) acc[a][i][q] = 0.f;

  // prologue: A(0)->AL0, B(0)->BL0, A(1)->AL1; VMC(4) leaves A(1) in flight
  stage_tile(Yb,        AL,         tid);
  stage_tile(BTb,       BL,         tid);
  stage_tile(Yb + 64,   AL + 16384, tid);
  VMC(4);
  BARR();

  for (int t = 0; t < 42; t += 6) {          // 6-tile unroll: lcm(2,3)
    TILE(t,     0, 0, 1, 1, VMC(4), BARR());
    TILE(t + 1, 1, 1, 1, 1, VMC(4), BARR());
    TILE(t + 2, 2, 0, 1, 1, VMC(4), BARR());
    TILE(t + 3, 0, 1, 1, 1, VMC(4), BARR());
    TILE(t + 4, 1, 0, 1, 1, VMC(4), BARR());
    TILE(t + 5, 2, 1, 1, 1, VMC(4), BARR());
  }
  TILE(42, 0, 0, 1, 1, VMC(4), BARR());
  TILE(43, 1, 1, 1, 1, VMC(4), BARR());
  TILE(44, 2, 0, 1, 1, VMC(4), BARR());
  TILE(45, 0, 1, 1, 1, VMC(4), BARR());      // stages B(46), A(47)
  TILE(46, 1, 0, 1, 0, VMC(0), BARR());      // stages B(47); drain all
  TILE(47, 2, 1, 0, 0, (void)0, (void)0);

  // epilogue: out = relu(acc + bias[o] + x)
  // 32x32 D-layout: col = lane&31, row = (q&3) + 8*(q>>2) + 4*(lane>>5)
#pragma unroll
  for (int a = 0; a < 4; ++a) {
    int mf = 2 * a + wr;
#pragma unroll
    for (int q = 0; q < 16; ++q) {
      int r = row0 + mf * 32 + (q & 3) + 8 * (q >> 2) + 4 * hi;
      int o = r & 63;
      int btl = r >> 6;
      int tt = btl % NT;
      int bb = b0 + btl / NT;
      float bo = bias[o];
      size_t obase = ((size_t)(bb * 64 + o) * NT + tt) * NN;
#pragma unroll
      for (int i = 0; i < 2; ++i) {
        int n = col0 + (4 * i + wc) * 32 + l31;
        size_t oidx = obase + n;
        float v = acc[a][i][q] + bo + x[oidx];
        out[oidx] = v > 0.f ? v : 0.f;
      }
    }
  }
}

extern "C" void kernel_launch(void* const* d_in, const int* in_sizes, int n_in,
                              void* d_out, int out_size, void* d_ws, size_t ws_size,
                              hipStream_t stream) {
  const float* x     = (const float*)d_in[0];
  const float* Lk    = (const float*)d_in[1];
  const float* theta = (const float*)d_in[2];
  const float* bias  = (const float*)d_in[3];
  float* out = (float*)d_out;

  char* ws = (char*)d_ws;
  short* BT = (short*)ws;                         // 6.29 MB
  short* Y  = (short*)(ws + (size_t)(8u << 20));  // up to 302 MB
  size_t avail = ws_size > ((size_t)8u << 20) ? ws_size - ((size_t)8u << 20) : 0;
  size_t perB = (size_t)NT * NC * KDIM * 2;       // 18,874,368 B per batch-row
  int bc = 16;
  while (bc > 1 && (size_t)bc * perB > avail) bc >>= 1;  // chunk over b if needed

  k_prep_bt<<<dim3(3072), dim3(256), 0, stream>>>(Lk, BT);
  for (int b0 = 0; b0 < NB; b0 += bc) {
    k_step1<<<dim3(bc * 384), dim3(256), 0, stream>>>(x, theta, Y, b0);
    int nwg = bc * 48;  // (bc*3072/256 rowb) * 4 colb, divisible by 8
    k_gemm<<<dim3(nwg), dim3(512), 0, stream>>>(Y, BT, x, bias, out, b0, nwg);
  }
}

// Round 13
// 506.518 us; speedup vs baseline: 1.0804x; 1.0804x over previous
//
#include <hip/hip_runtime.h>
#include <hip/hip_bf16.h>
#include <stdint.h>

// SpatioConvLayer: out = relu(x + b + einsum('iok,knm,bitm->botn', theta, Lk, x))
// (1) BT[n][k*1024+m] = bf16(Lk[k][n][m]); (2) Y[(b*48+t)*64+o][k*1024+m]
//     = sum_i theta[i,o,k] * x[b,i,t,m] (bf16, MFMA, LDS-staged x); (3) out =
//     Y @ BT^T fused bias+residual+relu, 256x256x64, 4 phases/K-tile.
// R13: faithful m201 phase discipline: {reads; stage; [lgkm(8)]; BAR;
//      lgkm(0); setprio(1); 16 MFMA; setprio(0); BAR} x4, NO sched_barrier
//      pinning, vmcnt(4) once per tile, MFMA 16x16x32, XOR swizzle, XCD swz.

typedef short bs8 __attribute__((ext_vector_type(8)));   // 8 x bf16 fragment
typedef float f32x4 __attribute__((ext_vector_type(4))); // MFMA accumulator

#define NB   16
#define NC   64
#define NT   48
#define NN   1024
#define NKS  3
#define KDIM 3072  // NKS * NN
#define KT   48    // KDIM / 64 K-tiles

// f32 -> bf16 round-to-nearest-even (finite inputs only)
__device__ __forceinline__ short f2bs(float f) {
  uint32_t u = __builtin_bit_cast(uint32_t, f);
  u = (u + 0x7FFFu + ((u >> 16) & 1u)) >> 16;
  return (short)u;
}

__device__ __forceinline__ void gload16(const void* g, void* l) {
  __builtin_amdgcn_global_load_lds(
      (const __attribute__((address_space(1))) void*)g,
      (__attribute__((address_space(3))) void*)l, 16, 0, 0);
}

// ---------------- prep: BT[n][k*NN+m] = bf16(Lk[k][n][m]) -------------------
__global__ __launch_bounds__(256) void k_prep_bt(const float* __restrict__ Lk,
                                                 short* __restrict__ BT) {
  int gid = blockIdx.x * 256 + threadIdx.x;
  int e = gid * 4;
  int k = e >> 20;
  int rem = e & 1048575;
  int n = rem >> 10;
  int m = rem & 1023;
  float4 v = *reinterpret_cast<const float4*>(Lk + e);
  union { short s[4]; uint64_t u; } p;
  p.s[0] = f2bs(v.x); p.s[1] = f2bs(v.y); p.s[2] = f2bs(v.z); p.s[3] = f2bs(v.w);
  *reinterpret_cast<uint64_t*>(BT + (size_t)n * KDIM + k * NN + m) = p.u;
}

// ---------------- step1: Y[btl*64+o][k*NN+m] = sum_i th[i,o,k] x[b,i,t,m] ---
__global__ __launch_bounds__(256, 2) void k_step1(const float* __restrict__ x,
                                                  const float* __restrict__ theta,
                                                  short* __restrict__ Y, int b0) {
  __shared__ __align__(16) short th[NKS * 64 * 72];  // [k][o][i] padded, 27.6KB
  __shared__ __align__(16) float xs[64 * 128];       // [i][m] slice, 32KB
  int tid = threadIdx.x;
  int wave = tid >> 6;
  for (int idx = tid; idx < NC * NC * NKS; idx += 256) {
    int i = idx / (NC * NKS);
    int r = idx - i * (NC * NKS);
    int o = r / NKS;
    int k = r - o * NKS;
    th[(k * 64 + o) * 72 + i] = f2bs(theta[idx]);  // theta[i][o][k]
  }

  int bid = blockIdx.x;
  int mt  = bid & 7;            // m-tile of 128
  int btl = bid >> 3;
  int b_l = btl / NT;
  int t   = btl - b_l * NT;
  int b   = b0 + b_l;
  const float* xb = x + (size_t)b * (NC * NT * NN) + (size_t)t * NN + mt * 128;

#pragma unroll
  for (int c = 0; c < 8; ++c) {
    int idx = c * 256 + tid;
    int row = idx >> 5, ch = idx & 31;
    gload16(xb + (size_t)row * (NT * NN) + ch * 4,
            xs + (c * 256 + wave * 64) * 4);  // wave-uniform base, 16B/lane
  }
  __syncthreads();  // drains vmcnt (xs) + lgkm (th)

  int lane = tid & 63;
  int l15 = lane & 15, lg = lane >> 4;
  size_t yrow0 = (size_t)btl * 64;

  for (int nni = 0; nni < 2; ++nni) {
    int mloc = wave * 32 + nni * 16 + l15;
    float xv[16];
#pragma unroll
    for (int j = 0; j < 16; ++j) {
      int i = ((j >> 3) << 5) + lg * 8 + (j & 7);
      xv[j] = xs[i * 128 + mloc];
    }
    f32x4 acc[3][4];
#pragma unroll
    for (int k = 0; k < 3; ++k)
#pragma unroll
      for (int mi = 0; mi < 4; ++mi)
        acc[k][mi] = (f32x4){0.f, 0.f, 0.f, 0.f};

#pragma unroll
    for (int ks = 0; ks < 2; ++ks) {
      bs8 bfrag;
#pragma unroll
      for (int j = 0; j < 8; ++j) bfrag[j] = f2bs(xv[ks * 8 + j]);
#pragma unroll
      for (int mi = 0; mi < 4; ++mi) {
#pragma unroll
        for (int k = 0; k < 3; ++k) {
          const bs8* ap = reinterpret_cast<const bs8*>(
              &th[(k * 64 + mi * 16 + l15) * 72 + ks * 32 + lg * 8]);
          acc[k][mi] = __builtin_amdgcn_mfma_f32_16x16x32_bf16(
              *ap, bfrag, acc[k][mi], 0, 0, 0);
        }
      }
    }
    int mcol = mt * 128 + mloc;
#pragma unroll
    for (int k = 0; k < 3; ++k)
#pragma unroll
      for (int mi = 0; mi < 4; ++mi)
#pragma unroll
        for (int q = 0; q < 4; ++q) {
          int o = mi * 16 + lg * 4 + q;
          Y[(yrow0 + o) * KDIM + k * NN + mcol] = f2bs(acc[k][mi][q]);
        }
  }
}

// ---------------- big GEMM: C = Y @ BT^T, 256^2, m201 phase discipline ------
// 8 waves 2M x 4N; phase order (0,0)->(0,1)->(1,1)->(1,0); frag reuse:
// A read P0/P2 (8), B0 read P0 (held to P3), B1 read P1 (reused P2).
// Per phase: reads; stage; [lgkm(8) if 12 reads]; BAR; lgkm(0);
// setprio(1); 16 MFMA; setprio(0); BAR.  No sched_barrier anywhere.
// Stage: P0:A1(t+1)->buf^1, P1:B1(t+1)->buf^1, P2:A0(t+2)->buf,
// P3:B0(t+2)->buf. vmcnt(4) after P3's MFMA, before its barrier: drains
// everything through {A1,B1}(t+1) => tile t+1 fully staged. Slot-overwrite
// gaps >= 2 barriers (R3 ledger). Tails: t=46 vmcnt(0); t=47 bare.
// Swizzle: LDS[row][c8] = g[row][c8 ^ (row&7)]; reader XORs (row&7)<<3.

__device__ __forceinline__ void stage_half(const short* __restrict__ src,
                                           short* lds, int h, int tid) {
  int wave = tid >> 6;
#pragma unroll
  for (int r = 0; r < 2; ++r) {
    int idx = h * 1024 + r * 512 + tid;
    int row = idx >> 3, c8 = idx & 7;
    int c8s = c8 ^ (row & 7);                     // inverse-swizzled source
    gload16(src + (size_t)row * KDIM + c8s * 8,
            lds + (h * 1024 + r * 512 + wave * 64) * 8);  // wave-uniform base
  }
}

#define VMC(N)  asm volatile("s_waitcnt vmcnt(" #N ")" ::: "memory")
#define LGKM(N) asm volatile("s_waitcnt lgkmcnt(" #N ")" ::: "memory")
#define BARR()  __builtin_amdgcn_s_barrier();

#define READ_A(DST, QM, P)                                                \
  _Pragma("unroll") for (int e = 0; e < 4; ++e)                           \
    _Pragma("unroll") for (int ks = 0; ks < 2; ++ks) {                    \
      int rw = (8 * (QM) + 2 * e + wr) * 16 + l15;                        \
      DST[e][ks] = *(const bs8*)&AL[(P) * 16384 + rw * 64 +               \
                    ((ks * 32 + lg * 8) ^ ((rw & 7) << 3))];              \
    }

#define READ_B(DST, QN, P)                                                \
  _Pragma("unroll") for (int f = 0; f < 2; ++f)                           \
    _Pragma("unroll") for (int ks = 0; ks < 2; ++ks) {                    \
      int rw = (8 * (QN) + 4 * f + wc) * 16 + l15;                        \
      DST[f][ks] = *(const bs8*)&BL[(P) * 16384 + rw * 64 +               \
                    ((ks * 32 + lg * 8) ^ ((rw & 7) << 3))];              \
    }

// ks-outer: dependent MFMAs on the same acc are 8 apart
#define COMPUTE(QM, AF, BF, QN)                                             \
  __builtin_amdgcn_s_setprio(1);                                            \
  _Pragma("unroll") for (int ks = 0; ks < 2; ++ks)                          \
    _Pragma("unroll") for (int e = 0; e < 4; ++e)                           \
      _Pragma("unroll") for (int f = 0; f < 2; ++f)                         \
        acc[4 * (QM) + e][2 * (QN) + f] =                                   \
            __builtin_amdgcn_mfma_f32_16x16x32_bf16(                        \
                AF[e][ks], BF[f][ks], acc[4 * (QM) + e][2 * (QN) + f],      \
                0, 0, 0);                                                   \
  __builtin_amdgcn_s_setprio(0);

// S1: t+1 exists (stage A1/B1); S2: t+2 exists (stage A0/B0); VM: tile vmcnt.
#define TILE(t, P, S1, S2, VM)                                              \
  {                                                                         \
    bs8 af[4][2], bf0[2][2], bf1[2][2];                                     \
    /* P0 */                                                                \
    READ_A(af, 0, P);                                                       \
    READ_B(bf0, 0, P);                                                      \
    if (S1) stage_half(Yb + ((t) + 1) * 64, AL + ((P) ^ 1) * 16384, 1, tid);\
    LGKM(8);                                                                \
    BARR();                                                                 \
    LGKM(0);                                                                \
    COMPUTE(0, af, bf0, 0);                                                 \
    BARR();                                                                 \
    /* P1 */                                                                \
    READ_B(bf1, 1, P);                                                      \
    if (S1) stage_half(BTb + ((t) + 1) * 64, BL + ((P) ^ 1) * 16384, 1, tid);\
    BARR();                                                                 \
    LGKM(0);                                                                \
    COMPUTE(0, af, bf1, 1);                                                 \
    BARR();                                                                 \
    /* P2 */                                                                \
    READ_A(af, 1, P);                                                       \
    if (S2) stage_half(Yb + ((t) + 2) * 64, AL + (P) * 16384, 0, tid);      \
    BARR();                                                                 \
    LGKM(0);                                                                \
    COMPUTE(1, af, bf1, 1);                                                 \
    BARR();                                                                 \
    /* P3 */                                                                \
    if (S2) stage_half(BTb + ((t) + 2) * 64, BL + (P) * 16384, 0, tid);     \
    BARR();                                                                 \
    COMPUTE(1, af, bf0, 0);                                                 \
    VM;                                                                     \
    BARR();                                                                 \
  }

__global__ __launch_bounds__(512, 2) void k_gemm(const short* __restrict__ Y,
                                                 const short* __restrict__ BT,
                                                 const float* __restrict__ x,
                                                 const float* __restrict__ bias,
                                                 float* __restrict__ out,
                                                 int b0, int nwg) {
  __shared__ __align__(16) short AL[2 * 16384];  // [buf][256][64] 64 KiB
  __shared__ __align__(16) short BL[2 * 16384];  // [buf][256][64] 64 KiB

  int bid = blockIdx.x;
  int cpx = nwg >> 3;                        // nwg % 8 == 0 -> bijective
  int swz = (bid & 7) * cpx + (bid >> 3);    // XCD-aware swizzle
  int colb = swz & 3;                        // 4 col-blocks (N=1024/256)
  int rowb = swz >> 2;

  int tid = threadIdx.x;
  int lane = tid & 63, wave = tid >> 6;
  int wr = wave >> 2, wc = wave & 3;         // 2M x 4N waves
  int l15 = lane & 15, lg = lane >> 4;
  int row0 = rowb * 256, col0 = colb * 256;

  const short* Yb  = Y  + (size_t)row0 * KDIM;
  const short* BTb = BT + (size_t)col0 * KDIM;

  f32x4 acc[8][4];
#pragma unroll
  for (int j = 0; j < 8; ++j)
#pragma unroll
    for (int i = 0; i < 4; ++i) acc[j][i] = (f32x4){0.f, 0.f, 0.f, 0.f};

  // prologue: tile0 (A0,A1,B0,B1) -> buf0; A0(1),B0(1) -> buf1 (12 loads)
  stage_half(Yb,        AL,         0, tid);
  stage_half(Yb,        AL,         1, tid);
  stage_half(BTb,       BL,         0, tid);
  stage_half(BTb,       BL,         1, tid);
  stage_half(Yb + 64,   AL + 16384, 0, tid);
  stage_half(BTb + 64,  BL + 16384, 0, tid);
  VMC(4);                                    // tile0 landed; {A0,B0}(1) fly
  BARR();

  for (int t = 0; t < KT - 2; t += 2) {
    TILE(t,     0, 1, 1, VMC(4));
    TILE(t + 1, 1, 1, 1, VMC(4));
  }
  TILE(KT - 2, 0, 1, 0, VMC(0));
  TILE(KT - 1, 1, 0, 0, (void)0);

  // epilogue: out = relu(acc + bias[o] + x); abs M-frag 2j+wr, N-frag 4i+wc
#pragma unroll
  for (int j = 0; j < 8; ++j) {
#pragma unroll
    for (int q = 0; q < 4; ++q) {
      int r = row0 + (2 * j + wr) * 16 + lg * 4 + q;  // chunk-local row
      int o = r & 63;
      int btl = r >> 6;
      int tt = btl % NT;
      int bb = b0 + btl / NT;
      float bo = bias[o];
      size_t obase = ((size_t)(bb * 64 + o) * NT + tt) * NN;
#pragma unroll
      for (int i = 0; i < 4; ++i) {
        int n = col0 + (4 * i + wc) * 16 + l15;
        size_t oidx = obase + n;
        float v = acc[j][i][q] + bo + x[oidx];
        out[oidx] = v > 0.f ? v : 0.f;
      }
    }
  }
}

extern "C" void kernel_launch(void* const* d_in, const int* in_sizes, int n_in,
                              void* d_out, int out_size, void* d_ws, size_t ws_size,
                              hipStream_t stream) {
  const float* x     = (const float*)d_in[0];
  const float* Lk    = (const float*)d_in[1];
  const float* theta = (const float*)d_in[2];
  const float* bias  = (const float*)d_in[3];
  float* out = (float*)d_out;

  char* ws = (char*)d_ws;
  short* BT = (short*)ws;                         // 6.29 MB
  short* Y  = (short*)(ws + (size_t)(8u << 20));  // up to 302 MB
  size_t avail = ws_size > ((size_t)8u << 20) ? ws_size - ((size_t)8u << 20) : 0;
  size_t perB = (size_t)NT * NC * KDIM * 2;       // 18,874,368 B per batch-row
  int bc = 16;
  while (bc > 1 && (size_t)bc * perB > avail) bc >>= 1;  // chunk over b if needed

  k_prep_bt<<<dim3(3072), dim3(256), 0, stream>>>(Lk, BT);
  for (int b0 = 0; b0 < NB; b0 += bc) {
    k_step1<<<dim3(bc * 384), dim3(256), 0, stream>>>(x, theta, Y, b0);
    int nwg = bc * 48;  // (bc*3072/256 rowb) * 4 colb, divisible by 8
    k_gemm<<<dim3(nwg), dim3(512), 0, stream>>>(Y, BT, x, bias, out, b0, nwg);
  }
}

// Round 14
// 481.961 us; speedup vs baseline: 1.1355x; 1.0510x over previous
//
#include <hip/hip_runtime.h>
#include <hip/hip_bf16.h>
#include <stdint.h>

// SpatioConvLayer: out = relu(x + b + einsum('iok,knm,bitm->botn', theta, Lk, x))
// (1) BT[n][k*1024+m] = bf16(Lk[k][n][m]); (2) Y[(b*48+t)*64+o][k*1024+m]
//     = sum_i theta[i,o,k] * x[b,i,t,m] (bf16, MFMA, LDS-staged x); (3) out =
//     Y @ BT^T fused bias+residual+relu, 256x256x64, 32x32x16 MFMA, 4 phases,
//     barrier between reads and COMPUTE (R10 champion structure).
// R14: bf1 read moved from P1 to P0 region -- the only read that was blocked
//     behind a barrier. Now every phase's ds_reads issue inside the previous
//     MFMA cluster's shadow; P1 is a zero-read phase. Liveness unchanged.

typedef short bs8 __attribute__((ext_vector_type(8)));     // 8 x bf16 fragment
typedef float f32x4 __attribute__((ext_vector_type(4)));   // 16x16 accumulator
typedef float f32x16 __attribute__((ext_vector_type(16))); // 32x32 accumulator

#define NB   16
#define NC   64
#define NT   48
#define NN   1024
#define NKS  3
#define KDIM 3072  // NKS * NN
#define KT   48    // KDIM / 64 K-tiles

// f32 -> bf16 round-to-nearest-even (finite inputs only)
__device__ __forceinline__ short f2bs(float f) {
  uint32_t u = __builtin_bit_cast(uint32_t, f);
  u = (u + 0x7FFFu + ((u >> 16) & 1u)) >> 16;
  return (short)u;
}

__device__ __forceinline__ void gload16(const void* g, void* l) {
  __builtin_amdgcn_global_load_lds(
      (const __attribute__((address_space(1))) void*)g,
      (__attribute__((address_space(3))) void*)l, 16, 0, 0);
}

// ---------------- prep: BT[n][k*NN+m] = bf16(Lk[k][n][m]) -------------------
__global__ __launch_bounds__(256) void k_prep_bt(const float* __restrict__ Lk,
                                                 short* __restrict__ BT) {
  int gid = blockIdx.x * 256 + threadIdx.x;
  int e = gid * 4;
  int k = e >> 20;
  int rem = e & 1048575;
  int n = rem >> 10;
  int m = rem & 1023;
  float4 v = *reinterpret_cast<const float4*>(Lk + e);
  union { short s[4]; uint64_t u; } p;
  p.s[0] = f2bs(v.x); p.s[1] = f2bs(v.y); p.s[2] = f2bs(v.z); p.s[3] = f2bs(v.w);
  *reinterpret_cast<uint64_t*>(BT + (size_t)n * KDIM + k * NN + m) = p.u;
}

// ---------------- step1: Y[btl*64+o][k*NN+m] = sum_i th[i,o,k] x[b,i,t,m] ---
__global__ __launch_bounds__(256, 2) void k_step1(const float* __restrict__ x,
                                                  const float* __restrict__ theta,
                                                  short* __restrict__ Y, int b0) {
  __shared__ __align__(16) short th[NKS * 64 * 72];  // [k][o][i] padded, 27.6KB
  __shared__ __align__(16) float xs[64 * 128];       // [i][m] slice, 32KB
  int tid = threadIdx.x;
  int wave = tid >> 6;
  for (int idx = tid; idx < NC * NC * NKS; idx += 256) {
    int i = idx / (NC * NKS);
    int r = idx - i * (NC * NKS);
    int o = r / NKS;
    int k = r - o * NKS;
    th[(k * 64 + o) * 72 + i] = f2bs(theta[idx]);  // theta[i][o][k]
  }

  int bid = blockIdx.x;
  int mt  = bid & 7;            // m-tile of 128
  int btl = bid >> 3;
  int b_l = btl / NT;
  int t   = btl - b_l * NT;
  int b   = b0 + b_l;
  const float* xb = x + (size_t)b * (NC * NT * NN) + (size_t)t * NN + mt * 128;

#pragma unroll
  for (int c = 0; c < 8; ++c) {
    int idx = c * 256 + tid;
    int row = idx >> 5, ch = idx & 31;
    gload16(xb + (size_t)row * (NT * NN) + ch * 4,
            xs + (c * 256 + wave * 64) * 4);  // wave-uniform base, 16B/lane
  }
  __syncthreads();  // drains vmcnt (xs) + lgkm (th)

  int lane = tid & 63;
  int l15 = lane & 15, lg = lane >> 4;
  size_t yrow0 = (size_t)btl * 64;

  for (int nni = 0; nni < 2; ++nni) {
    int mloc = wave * 32 + nni * 16 + l15;
    float xv[16];
#pragma unroll
    for (int j = 0; j < 16; ++j) {
      int i = ((j >> 3) << 5) + lg * 8 + (j & 7);
      xv[j] = xs[i * 128 + mloc];
    }
    f32x4 acc[3][4];
#pragma unroll
    for (int k = 0; k < 3; ++k)
#pragma unroll
      for (int mi = 0; mi < 4; ++mi)
        acc[k][mi] = (f32x4){0.f, 0.f, 0.f, 0.f};

#pragma unroll
    for (int ks = 0; ks < 2; ++ks) {
      bs8 bfrag;
#pragma unroll
      for (int j = 0; j < 8; ++j) bfrag[j] = f2bs(xv[ks * 8 + j]);
#pragma unroll
      for (int mi = 0; mi < 4; ++mi) {
#pragma unroll
        for (int k = 0; k < 3; ++k) {
          const bs8* ap = reinterpret_cast<const bs8*>(
              &th[(k * 64 + mi * 16 + l15) * 72 + ks * 32 + lg * 8]);
          acc[k][mi] = __builtin_amdgcn_mfma_f32_16x16x32_bf16(
              *ap, bfrag, acc[k][mi], 0, 0, 0);
        }
      }
    }
    int mcol = mt * 128 + mloc;
#pragma unroll
    for (int k = 0; k < 3; ++k)
#pragma unroll
      for (int mi = 0; mi < 4; ++mi)
#pragma unroll
        for (int q = 0; q < 4; ++q) {
          int o = mi * 16 + lg * 4 + q;
          Y[(yrow0 + o) * KDIM + k * NN + mcol] = f2bs(acc[k][mi][q]);
        }
  }
}

// ---------------- big GEMM: C = Y @ BT^T, 256^2, 32x32x16, 4-phase ----------
// 8 waves 2M x 4N (wr = wave>>2, wc = wave&3). Phase order (MP,NI) =
// (0,0)->(0,1)->(1,1)->(1,0). Frag reuse: af read P0(8)+P2(8), bf0 read
// P0(4, held to P3), bf1 read P0(4, used P1/P2) [R14: moved from P1 -- the
// only read that was barrier-blocked; all reads now issue in MFMA shadows].
// Stream: [R(af0,bf0,bf1); stageA1'; BAR][C(0,bf0,0); stageB1'; BAR]
//         [C(0,bf1,1); R(af1); stageA0''; BAR][C(1,bf1,1); stageB0'';
//          VMC(4); BAR][C(1,bf0,0); -> next tile reads...]
// Stage-slot safety (2-phase rule: stage issued >= 2 phase-barriers after
// slot's last read, whose consuming COMPUTE certifies completion at the
// next barrier): A0 read P0/staged P2 (2); B0 read P0/final use P3-compute,
// staged P3 pre-BAR3 -> overwrites B0(t-2)... B0 slot in buf p holds B0(t),
// staged with B0(t+2): last read P0(t), cert BAR1(t), stage P3(t) (3) ok.
// A1 slot: read P2(t-1), cert BAR3(t-1), stage P0(t) (2) ok. B1 slot: read
// P0(t-1) [R14 move makes this EARLIER], cert BAR1(t-1), stage P1(t) (4) ok.
// vmcnt(4) at P3 drains through {A1,B1}(t+1). Tails: t=46 VMC(0), t=47 bare.
// Swizzle g(row) = (row&7)^((row>>3)&3), inverse-applied on staging source.

__device__ __forceinline__ void stage_half(const short* __restrict__ src,
                                           short* lds, int h, int tid) {
  int wave = tid >> 6;
#pragma unroll
  for (int r = 0; r < 2; ++r) {
    int idx = h * 1024 + r * 512 + tid;
    int row = idx >> 3, c8 = idx & 7;
    int c8s = c8 ^ (row & 7) ^ ((row >> 3) & 3);  // inverse-swizzled source
    gload16(src + (size_t)row * KDIM + c8s * 8,
            lds + (h * 1024 + r * 512 + wave * 64) * 8);  // wave-uniform base
  }
}

#define VMC(N) asm volatile("s_waitcnt vmcnt(" #N ")" ::: "memory")
#define BARR() __builtin_amdgcn_s_barrier();

#define READ_A32(DST, MP, P)                                                \
  _Pragma("unroll") for (int e = 0; e < 2; ++e)                             \
    _Pragma("unroll") for (int ks = 0; ks < 4; ++ks) {                      \
      int row = (4 * (MP) + 2 * e + wr) * 32 + l31;                         \
      int ch = (2 * ks + hi) ^ (row & 7) ^ ((row >> 3) & 3);                \
      DST[e][ks] = *(const bs8*)&AL[(P) * 16384 + row * 64 + ch * 8];       \
    }

#define READ_B32(DST, NI, P)                                                \
  _Pragma("unroll") for (int ks = 0; ks < 4; ++ks) {                        \
    int row = (4 * (NI) + wc) * 32 + l31;                                   \
    int ch = (2 * ks + hi) ^ (row & 7) ^ ((row >> 3) & 3);                  \
    DST[ks] = *(const bs8*)&BL[(P) * 16384 + row * 64 + ch * 8];            \
  }

// ks-outer: the 2 accs of a phase rotate (dep distance 2)
#define COMPUTE32(MP, BF, NI)                                               \
  __builtin_amdgcn_s_setprio(1);                                            \
  _Pragma("unroll") for (int ks = 0; ks < 4; ++ks)                          \
    _Pragma("unroll") for (int e = 0; e < 2; ++e)                           \
      acc[2 * (MP) + e][(NI)] = __builtin_amdgcn_mfma_f32_32x32x16_bf16(    \
          af[e][ks], BF[ks], acc[2 * (MP) + e][(NI)], 0, 0, 0);             \
  __builtin_amdgcn_s_setprio(0);

// S1: t+1 exists (stage A1/B1); S2: t+2 exists (stage A0/B0); VM: tile vmcnt.
#define TILE(t, P, S1, S2, VM)                                              \
  {                                                                         \
    bs8 af[2][4], bf0[4], bf1[4];                                           \
    READ_A32(af, 0, P);                                                     \
    READ_B32(bf0, 0, P);                                                    \
    READ_B32(bf1, 1, P);  /* R14: read-ahead, was in P1 */                  \
    if (S1) stage_half(Yb + ((t) + 1) * 64, AL + ((P) ^ 1) * 16384, 1, tid);\
    BARR();                                                                 \
    COMPUTE32(0, bf0, 0);                                                   \
    if (S1) stage_half(BTb + ((t) + 1) * 64, BL + ((P) ^ 1) * 16384, 1, tid);\
    BARR();                                                                 \
    COMPUTE32(0, bf1, 1);                                                   \
    READ_A32(af, 1, P);                                                     \
    if (S2) stage_half(Yb + ((t) + 2) * 64, AL + (P) * 16384, 0, tid);      \
    BARR();                                                                 \
    COMPUTE32(1, bf1, 1);                                                   \
    if (S2) stage_half(BTb + ((t) + 2) * 64, BL + (P) * 16384, 0, tid);     \
    VM;                                                                     \
    BARR();                                                                 \
    COMPUTE32(1, bf0, 0);                                                   \
  }

__global__ __launch_bounds__(512, 2) void k_gemm(const short* __restrict__ Y,
                                                 const short* __restrict__ BT,
                                                 const float* __restrict__ x,
                                                 const float* __restrict__ bias,
                                                 float* __restrict__ out,
                                                 int b0, int nwg) {
  __shared__ __align__(16) short AL[2 * 16384];  // [buf][256][64] 64 KiB
  __shared__ __align__(16) short BL[2 * 16384];  // [buf][256][64] 64 KiB

  int bid = blockIdx.x;
  int cpx = nwg >> 3;                        // nwg % 8 == 0 -> bijective
  int swz = (bid & 7) * cpx + (bid >> 3);    // XCD-aware swizzle
  int colb = swz & 3;                        // 4 col-blocks (N=1024/256)
  int rowb = swz >> 2;

  int tid = threadIdx.x;
  int lane = tid & 63, wave = tid >> 6;
  int wr = wave >> 2, wc = wave & 3;         // 2M x 4N waves
  int l31 = lane & 31, hi = lane >> 5;
  int row0 = rowb * 256, col0 = colb * 256;

  const short* Yb  = Y  + (size_t)row0 * KDIM;
  const short* BTb = BT + (size_t)col0 * KDIM;

  f32x16 acc[4][2];                          // [a = 2MP+e][NI]; mf = 2a+wr
#pragma unroll
  for (int a = 0; a < 4; ++a)
#pragma unroll
    for (int i = 0; i < 2; ++i)
#pragma unroll
      for (int q = 0; q < 16; ++q) acc[a][i][q] = 0.f;

  // prologue: tile0 (A0,A1,B0,B1) -> buf0; A0(1),B0(1) -> buf1 (12 loads)
  stage_half(Yb,        AL,         0, tid);
  stage_half(Yb,        AL,         1, tid);
  stage_half(BTb,       BL,         0, tid);
  stage_half(BTb,       BL,         1, tid);
  stage_half(Yb + 64,   AL + 16384, 0, tid);
  stage_half(BTb + 64,  BL + 16384, 0, tid);
  VMC(4);                                    // tile0 landed; {A0,B0}(1) fly
  BARR();

  for (int t = 0; t < KT - 2; t += 2) {
    TILE(t,     0, 1, 1, VMC(4));
    TILE(t + 1, 1, 1, 1, VMC(4));
  }
  TILE(KT - 2, 0, 1, 0, VMC(0));
  TILE(KT - 1, 1, 0, 0, (void)0);

  // epilogue: out = relu(acc + bias[o] + x)
  // 32x32 D-layout: col = lane&31, row = (q&3) + 8*(q>>2) + 4*(lane>>5)
#pragma unroll
  for (int a = 0; a < 4; ++a) {
    int mf = 2 * a + wr;
#pragma unroll
    for (int q = 0; q < 16; ++q) {
      int r = row0 + mf * 32 + (q & 3) + 8 * (q >> 2) + 4 * hi;
      int o = r & 63;
      int btl = r >> 6;
      int tt = btl % NT;
      int bb = b0 + btl / NT;
      float bo = bias[o];
      size_t obase = ((size_t)(bb * 64 + o) * NT + tt) * NN;
#pragma unroll
      for (int i = 0; i < 2; ++i) {
        int n = col0 + (4 * i + wc) * 32 + l31;
        size_t oidx = obase + n;
        float v = acc[a][i][q] + bo + x[oidx];
        out[oidx] = v > 0.f ? v : 0.f;
      }
    }
  }
}

extern "C" void kernel_launch(void* const* d_in, const int* in_sizes, int n_in,
                              void* d_out, int out_size, void* d_ws, size_t ws_size,
                              hipStream_t stream) {
  const float* x     = (const float*)d_in[0];
  const float* Lk    = (const float*)d_in[1];
  const float* theta = (const float*)d_in[2];
  const float* bias  = (const float*)d_in[3];
  float* out = (float*)d_out;

  char* ws = (char*)d_ws;
  short* BT = (short*)ws;                         // 6.29 MB
  short* Y  = (short*)(ws + (size_t)(8u << 20));  // up to 302 MB
  size_t avail = ws_size > ((size_t)8u << 20) ? ws_size - ((size_t)8u << 20) : 0;
  size_t perB = (size_t)NT * NC * KDIM * 2;       // 18,874,368 B per batch-row
  int bc = 16;
  while (bc > 1 && (size_t)bc * perB > avail) bc >>= 1;  // chunk over b if needed

  k_prep_bt<<<dim3(3072), dim3(256), 0, stream>>>(Lk, BT);
  for (int b0 = 0; b0 < NB; b0 += bc) {
    k_step1<<<dim3(bc * 384), dim3(256), 0, stream>>>(x, theta, Y, b0);
    int nwg = bc * 48;  // (bc*3072/256 rowb) * 4 colb, divisible by 8
    k_gemm<<<dim3(nwg), dim3(512), 0, stream>>>(Y, BT, x, bias, out, b0, nwg);
  }
}